// Round 11
// baseline (127.459 us; speedup 1.0000x reference)
//
#include <hip/hip_runtime.h>
#include <hip/hip_bf16.h>

#define M_DIM 4096
#define N_DIM 8192
#define D_DIM 256
#define NSLICE 32                    /* 256-col slices of N */
#define NREP 3                       /* instrumentation: x3 gemm body so the
                                        dispatch tops the rocprof table */
#define C_EXP (-0.7213475204444817f) /* -1/(2 ln2): exp(-d/2) = 2^(d*C_EXP) */
#define K_ACC (1.4426950408889634f)  /* -2*C_EXP: acc coefficient */
#define SKIP_THR (-151.0f)           /* exp2f(x)==0.0f exactly for x<=-151 */

#define AS1 __attribute__((address_space(1)))
#define AS3 __attribute__((address_space(3)))

typedef __attribute__((ext_vector_type(8))) short short8; // 8 bf16 = 4 VGPR
typedef __attribute__((ext_vector_type(4))) float f32x4;  // MFMA C/D frag

__device__ inline unsigned short f2bf(float f) {
    __hip_bfloat16 h = __float2bfloat16(f);
    return *reinterpret_cast<unsigned short*>(&h);
}

// ---------------------------------------------------------------------------
// prep: fp32 -> bf16 rows; X rows: sq1[r] = ||x||^2 * C_EXP; X_train rows:
// sqal[r] = {||t||^2 * C_EXP, alpha[r]}.
// ---------------------------------------------------------------------------
__global__ __launch_bounds__(256) void prep_kernel(
    const float* __restrict__ X, const float* __restrict__ T,
    const float* __restrict__ alpha,
    unsigned short* __restrict__ Xb, unsigned short* __restrict__ Tb,
    float* __restrict__ sq1, float2* __restrict__ sqal)
{
    const int row  = blockIdx.x * 4 + (threadIdx.x >> 6);
    const int lane = threadIdx.x & 63;
    const float* src; unsigned short* dst; int r; bool isX;
    if (row < M_DIM) { src = X; dst = Xb; r = row; isX = true; }
    else             { src = T; dst = Tb; r = row - M_DIM; isX = false; }

    const float4* s4 = reinterpret_cast<const float4*>(src + (size_t)r * D_DIM);
    float4 v = s4[lane];
    float ss = v.x * v.x + v.y * v.y + v.z * v.z + v.w * v.w;

    ushort4 b4;
    b4.x = f2bf(v.x); b4.y = f2bf(v.y); b4.z = f2bf(v.z); b4.w = f2bf(v.w);
    reinterpret_cast<ushort4*>(dst + (size_t)r * D_DIM)[lane] = b4;

    #pragma unroll
    for (int o = 1; o < 64; o <<= 1) ss += __shfl_xor(ss, o);
    if (lane == 0) {
        if (isX) sq1[r] = ss * C_EXP;
        else     sqal[r] = make_float2(ss * C_EXP, alpha[r]);
    }
}

// ---------------------------------------------------------------------------
// Fused RBF GEMM — R10 structure, INSTRUMENTED: the full gemm body (acc init
// -> staging pipeline -> K-loop -> epilogue -> part store) runs NREP=3 times
// producing identical output each rep. Purpose: raise this dispatch above the
// harness's 41 us ws-poison fills so rocprof's top-5 finally shows the
// gemm's own MfmaUtil / VALUBusy / LDS-conflict / occupancy counters.
// Each rep is self-contained for vmcnt counting (ends fully drained);
// __syncthreads() at rep top fences the epilogue's red[]-in-buf0 reads
// against the next rep's prologue stages into the same LDS region.
// (Schedule/geometry unchanged from R10 — see R10 comments.)
// ---------------------------------------------------------------------------
__global__ __launch_bounds__(512, 2) void gemm_kernel(
    const unsigned short* __restrict__ Xb, const unsigned short* __restrict__ Tb,
    const float* __restrict__ sq1, const float2* __restrict__ sqal,
    float* __restrict__ part)
{
    __shared__ __align__(16) char smem[131072];
    const int bn   = blockIdx.x & 31;
    const int bm   = blockIdx.x >> 5;
    const int tid  = threadIdx.x;
    const int wid  = tid >> 6;
    const int lane = tid & 63;
    const int l15  = lane & 15, lg = lane >> 4, xr = l15 & 7;
    const int wr   = wid >> 2, wc = wid & 3;   // 2x4 waves, 128x64 out each
    const int rsub = lane >> 3;
    const int sg16 = ((lane & 7) ^ rsub) * 16; // inverse-swizzled src slot

    const char* XbB = (const char*)Xb;
    const char* TbB = (const char*)Tb;

    auto stage2 = [&](int ktn, int p) {
        if (ktn > 3) return;
        #pragma unroll
        for (int c = 0; c < 2; ++c) {
            const int g = wid + 8 * (2 * p + c);
            const int h = g >> 4, blk = g & 15;
            const int dest = (ktn & 1) * 65536 + (h & 1) * 32768
                           + (h >> 1) * 16384 + blk * 1024;
            const char* sb = (h < 2) ? XbB : TbB;
            const int rc = ((h < 2) ? bm : bn) * 256 + (h & 1) * 128
                         + blk * 8 + rsub;
            const size_t src = (size_t)rc * 512 + (size_t)(ktn * 128 + sg16);
            __builtin_amdgcn_global_load_lds(
                (const AS1 void*)(sb + src), (AS3 void*)(smem + dest), 16, 0, 0);
        }
    };

    #pragma unroll 1
    for (int rep = 0; rep < NREP; ++rep) {
        __syncthreads();   // fence prior rep's red[] reads vs our buf0 stages

        f32x4 acc[8][4];
        #pragma unroll
        for (int m = 0; m < 8; ++m)
            #pragma unroll
            for (int n = 0; n < 4; ++n) acc[m][n] = (f32x4)0.0f;

        // prologue: stage all of kt0
        #pragma unroll
        for (int p = 0; p < 4; ++p) stage2(0, p);

        short8 af0[4][2], af1[4][2], bf0[2][2], bf1[2][2];

        #pragma unroll
        for (int kt = 0; kt < 4; ++kt) {
            const char* Abase = smem + (kt & 1) * 65536 + wr * 32768;
            const char* Bbase = smem + (kt & 1) * 65536 + 16384 + (wc >> 1) * 32768
                              + ((wc & 1) * 64) * 128;

            // ---- P0: (mh0, nh0) — fenced barrier, counted vmcnt ----
            stage2(kt + 1, 0);
            if (kt < 3) asm volatile("s_waitcnt vmcnt(2)" ::: "memory");
            else        asm volatile("s_waitcnt vmcnt(0)" ::: "memory");
            asm volatile("s_barrier" ::: "memory");   // landed-buffer guarantee
            #pragma unroll
            for (int m = 0; m < 4; ++m)
                #pragma unroll
                for (int ks = 0; ks < 2; ++ks)
                    af0[m][ks] = *(const short8*)(Abase + (m * 16 + l15) * 128
                                                  + (((ks * 4 + lg) ^ xr)) * 16);
            #pragma unroll
            for (int n = 0; n < 2; ++n)
                #pragma unroll
                for (int ks = 0; ks < 2; ++ks)
                    bf0[n][ks] = *(const short8*)(Bbase + (n * 16 + l15) * 128
                                                  + (((ks * 4 + lg) ^ xr)) * 16);
            __builtin_amdgcn_s_setprio(1);
            #pragma unroll
            for (int ks = 0; ks < 2; ++ks)
                #pragma unroll
                for (int m = 0; m < 4; ++m)
                    #pragma unroll
                    for (int n = 0; n < 2; ++n)
                        acc[m][n] = __builtin_amdgcn_mfma_f32_16x16x32_bf16(
                            af0[m][ks], bf0[n][ks], acc[m][n], 0, 0, 0);
            __builtin_amdgcn_s_setprio(0);
            __builtin_amdgcn_s_barrier();

            // ---- P1: (mh0, nh1) ----
            #pragma unroll
            for (int n = 0; n < 2; ++n)
                #pragma unroll
                for (int ks = 0; ks < 2; ++ks)
                    bf1[n][ks] = *(const short8*)(Bbase + (32 + n * 16 + l15) * 128
                                                  + (((ks * 4 + lg) ^ xr)) * 16);
            stage2(kt + 1, 1);
            __builtin_amdgcn_s_setprio(1);
            #pragma unroll
            for (int ks = 0; ks < 2; ++ks)
                #pragma unroll
                for (int m = 0; m < 4; ++m)
                    #pragma unroll
                    for (int n = 0; n < 2; ++n)
                        acc[m][2 + n] = __builtin_amdgcn_mfma_f32_16x16x32_bf16(
                            af0[m][ks], bf1[n][ks], acc[m][2 + n], 0, 0, 0);
            __builtin_amdgcn_s_setprio(0);
            __builtin_amdgcn_s_barrier();

            // ---- P2: (mh1, nh1) ----
            #pragma unroll
            for (int m = 0; m < 4; ++m)
                #pragma unroll
                for (int ks = 0; ks < 2; ++ks)
                    af1[m][ks] = *(const short8*)(Abase + (64 + m * 16 + l15) * 128
                                                  + (((ks * 4 + lg) ^ xr)) * 16);
            stage2(kt + 1, 2);
            __builtin_amdgcn_s_setprio(1);
            #pragma unroll
            for (int ks = 0; ks < 2; ++ks)
                #pragma unroll
                for (int m = 0; m < 4; ++m)
                    #pragma unroll
                    for (int n = 0; n < 2; ++n)
                        acc[4 + m][2 + n] = __builtin_amdgcn_mfma_f32_16x16x32_bf16(
                            af1[m][ks], bf1[n][ks], acc[4 + m][2 + n], 0, 0, 0);
            __builtin_amdgcn_s_setprio(0);
            __builtin_amdgcn_s_barrier();

            // ---- P3: (mh1, nh0) ----
            stage2(kt + 1, 3);
            __builtin_amdgcn_s_setprio(1);
            #pragma unroll
            for (int ks = 0; ks < 2; ++ks)
                #pragma unroll
                for (int m = 0; m < 4; ++m)
                    #pragma unroll
                    for (int n = 0; n < 2; ++n)
                        acc[4 + m][n] = __builtin_amdgcn_mfma_f32_16x16x32_bf16(
                            af1[m][ks], bf0[n][ks], acc[4 + m][n], 0, 0, 0);
            __builtin_amdgcn_s_setprio(0);
            __builtin_amdgcn_s_barrier();
        }

        // ---- Epilogue: exp2 + alpha-weighted row reduce ----
        const int rowbase = bm * 256 + wr * 128;
        float4 s1v[8];
        #pragma unroll
        for (int m = 0; m < 8; ++m)
            s1v[m] = *reinterpret_cast<const float4*>(sq1 + rowbase + m * 16 + lg * 4);
        float2 sa[4];
        #pragma unroll
        for (int n = 0; n < 4; ++n)
            sa[n] = sqal[bn * 256 + wc * 64 + n * 16 + l15];

        float amax = acc[0][0][0], s1m = s1v[0][0], s2m = sa[0].x;
        #pragma unroll
        for (int m = 0; m < 8; ++m)
            #pragma unroll
            for (int n = 0; n < 4; ++n)
                #pragma unroll
                for (int r = 0; r < 4; ++r) amax = fmaxf(amax, acc[m][n][r]);
        #pragma unroll
        for (int m = 0; m < 8; ++m)
            #pragma unroll
            for (int r = 0; r < 4; ++r) s1m = fmaxf(s1m, s1v[m][r]);
        #pragma unroll
        for (int n = 0; n < 4; ++n) s2m = fmaxf(s2m, sa[n].x);

        float psum[8][4];
        #pragma unroll
        for (int m = 0; m < 8; ++m)
            #pragma unroll
            for (int r = 0; r < 4; ++r) psum[m][r] = 0.0f;

        const float bound = fmaf(amax, K_ACC, s1m + s2m); // >= every arg
        if (!__all(bound < SKIP_THR)) {
            #pragma unroll
            for (int m = 0; m < 8; ++m)
                #pragma unroll
                for (int n = 0; n < 4; ++n)
                    #pragma unroll
                    for (int r = 0; r < 4; ++r) {
                        const float arg = fmaf(acc[m][n][r], K_ACC, s1v[m][r] + sa[n].x);
                        psum[m][r] = fmaf(__builtin_amdgcn_exp2f(arg), sa[n].y, psum[m][r]);
                    }
        }

        // 16-lane (l15) shuffle reduce -> cross-wave (wc) via LDS
        float* red = (float*)smem;
        #pragma unroll
        for (int m = 0; m < 8; ++m) {
            float4 pv;
            #pragma unroll
            for (int r = 0; r < 4; ++r) {
                float p = psum[m][r];
                p += __shfl_xor(p, 1);
                p += __shfl_xor(p, 2);
                p += __shfl_xor(p, 4);
                p += __shfl_xor(p, 8);
                ((float*)&pv)[r] = p;
            }
            if (l15 == 0)
                *reinterpret_cast<float4*>(&red[wc * 256 + wr * 128 + m * 16 + lg * 4]) = pv;
        }
        __syncthreads();
        if (tid < 256) {
            const float s = red[tid] + red[256 + tid] + red[512 + tid] + red[768 + tid];
            part[(size_t)bn * M_DIM + bm * 256 + tid] = s;
        }
    }
}

// ---------------------------------------------------------------------------
// reduce: out[i] = sum over 32 col-slices of part[cs][i]. 16 blocks x 256.
// ---------------------------------------------------------------------------
__global__ __launch_bounds__(256) void reduce_kernel(
    const float* __restrict__ part, float* __restrict__ out)
{
    const int gi = blockIdx.x * 256 + threadIdx.x;
    float s = 0.0f;
    #pragma unroll
    for (int b = 0; b < NSLICE; ++b) s += part[(size_t)b * M_DIM + gi];
    out[gi] = s;
}

extern "C" void kernel_launch(void* const* d_in, const int* in_sizes, int n_in,
                              void* d_out, int out_size, void* d_ws, size_t ws_size,
                              hipStream_t stream)
{
    const float* X  = (const float*)d_in[0];
    const float* T  = (const float*)d_in[1];
    const float* al = (const float*)d_in[2];
    float* out = (float*)d_out;

    char* ws = (char*)d_ws;
    unsigned short* Xb = (unsigned short*)ws;                               // 2 MiB
    unsigned short* Tb = (unsigned short*)(ws + (size_t)M_DIM * D_DIM * 2); // 4 MiB
    float* sq1  = (float*)(ws + (size_t)(M_DIM + N_DIM) * D_DIM * 2);       // 16 KiB
    float2* sqal = (float2*)(sq1 + M_DIM);                                  // 64 KiB
    float* part = (float*)(sqal + N_DIM);                                   // 512 KiB

    prep_kernel<<<(M_DIM + N_DIM) / 4, 256, 0, stream>>>(X, T, al, Xb, Tb, sq1, sqal);
    gemm_kernel<<<(M_DIM / 256) * NSLICE, 512, 0, stream>>>(Xb, Tb, sq1, sqal, part);
    reduce_kernel<<<M_DIM / 256, 256, 0, stream>>>(part, out);
}

// Round 12
// 35.886 us; speedup vs baseline: 3.5518x; 3.5518x over previous
//
#include <hip/hip_runtime.h>
#include <hip/hip_bf16.h>

#define M_DIM 4096
#define N_DIM 8192
#define D_DIM 256
#define NSLICE 32                    /* 256-col slices of N */
#define C_EXP (-0.7213475204444817f) /* -1/(2 ln2): exp(-d/2) = 2^(d*C_EXP) */
#define K_ACC (1.4426950408889634f)  /* -2*C_EXP: acc coefficient */
#define SKIP_THR (-151.0f)           /* exp2f(x)==0.0f exactly for x<=-151 */

#define AS1 __attribute__((address_space(1)))
#define AS3 __attribute__((address_space(3)))

typedef __attribute__((ext_vector_type(8))) short short8; // 8 bf16 = 4 VGPR
typedef __attribute__((ext_vector_type(4))) float f32x4;  // MFMA C/D frag

__device__ inline unsigned short f2bf(float f) {
    __hip_bfloat16 h = __float2bfloat16(f);
    return *reinterpret_cast<unsigned short*>(&h);
}

// ---------------------------------------------------------------------------
// prep: fp32 -> bf16 rows; X rows: sq1[r] = ||x||^2 * C_EXP; X_train rows:
// sqal[r] = {||t||^2 * C_EXP, alpha[r]}.
// ---------------------------------------------------------------------------
__global__ __launch_bounds__(256) void prep_kernel(
    const float* __restrict__ X, const float* __restrict__ T,
    const float* __restrict__ alpha,
    unsigned short* __restrict__ Xb, unsigned short* __restrict__ Tb,
    float* __restrict__ sq1, float2* __restrict__ sqal)
{
    const int row  = blockIdx.x * 4 + (threadIdx.x >> 6);
    const int lane = threadIdx.x & 63;
    const float* src; unsigned short* dst; int r; bool isX;
    if (row < M_DIM) { src = X; dst = Xb; r = row; isX = true; }
    else             { src = T; dst = Tb; r = row - M_DIM; isX = false; }

    const float4* s4 = reinterpret_cast<const float4*>(src + (size_t)r * D_DIM);
    float4 v = s4[lane];
    float ss = v.x * v.x + v.y * v.y + v.z * v.z + v.w * v.w;

    ushort4 b4;
    b4.x = f2bf(v.x); b4.y = f2bf(v.y); b4.z = f2bf(v.z); b4.w = f2bf(v.w);
    reinterpret_cast<ushort4*>(dst + (size_t)r * D_DIM)[lane] = b4;

    #pragma unroll
    for (int o = 1; o < 64; o <<= 1) ss += __shfl_xor(ss, o);
    if (lane == 0) {
        if (isX) sq1[r] = ss * C_EXP;
        else     sqal[r] = make_float2(ss * C_EXP, alpha[r]);
    }
}

// ---------------------------------------------------------------------------
// Fused RBF GEMM — R10 phased schedule + R11's diagnosis fixed:
//  (a) Mapping-robust 2D block swizzle: per-XCD working set <= 2.5 MB under
//      BOTH round-robin(%8) and chunked(/64) block->XCD mappings -> staging
//      re-reads hit the 4 MB per-XCD L2 (R11: 37 MB/rep L2 misses at 930
//      GB/s WAS the kernel time).
//  (b) Phase-matched staging: phase p stages exactly the quadrant consumed
//      at phase p of tile kt+1 (P0: af0/bf0 regions, 4 ops/wave; P1: bf1,
//      2; P2: af1, 2; P3: none). Waits vmcnt(8)@P0/P1/P2 (tail 4/2/0):
//      every staged byte has a FULL 4-phase (~600 cyc) lookahead, covering
//      L2/L3 miss latency (R11: youngest ops had ~1 phase -> serialized).
//  One leading {wait, asm s_barrier} per read-phase (12 barriers vs R10's
//  20). Race analysis: unit U of tile t+2 is staged at t+1's phase p, which
//  every wave reaches only after passing t+1 P0's barrier, i.e. after the
//  slowest wave finished ALL of tile t (last reader of that buffer). P3 is
//  register-only (no barrier needed). vmcnt counting exact: K-loop's only
//  VMEM is the stage stream; per-wave waits are made cross-wave-safe by the
//  barrier that follows them.
// Geometry: 256x256 tile, 8 waves (2x4), wave tile 128x64, acc[8][4], BK=64
// (4 K-tiles), 2 x 64 KB ping-pong LDS. LDS 16B-slot swizzle s'=s^(row&7)
// both sides (G21; 0 conflicts measured R11).
// Layouts (m89/m91): A/B lane l: row/col=l&15, k=(l>>4)*8..+7 per 32-k
// window; C/D: col=lane&15, row=(lane>>4)*4+reg.
// ---------------------------------------------------------------------------
__global__ __launch_bounds__(512, 2) void gemm_kernel(
    const unsigned short* __restrict__ Xb, const unsigned short* __restrict__ Tb,
    const float* __restrict__ sq1, const float2* __restrict__ sqal,
    float* __restrict__ part)
{
    __shared__ __align__(16) char smem[131072];
    // Mapping-robust decode: round-robin XCD x -> bn:{4g+(x&3)}g=0..7 (8) +
    // bm: 8 values = 2 MB; chunked XCD x=g -> bn:{4x..4x+3} + bm: all 16
    // = 2.5 MB. Both fit 4 MB L2.
    const int g    = blockIdx.x >> 6;         // 0..7
    const int r    = blockIdx.x & 63;
    const int bn   = g * 4 + (r & 3);         // 0..31
    const int bm   = r >> 2;                  // 0..15
    const int tid  = threadIdx.x;
    const int wid  = tid >> 6;
    const int lane = tid & 63;
    const int l15  = lane & 15, lg = lane >> 4, xr = l15 & 7;
    const int wr   = wid >> 2, wc = wid & 3;  // 2x4 waves, 128x64 out each
    const int rsub = lane >> 3;
    const int sg16 = ((lane & 7) ^ rsub) * 16; // inverse-swizzled src slot

    const char* XbB = (const char*)Xb;
    const char* TbB = (const char*)Tb;

    // One 1 KB stage op: region h (0=A rows 0-127 @0, 1=A 128-255 @32K,
    // 2=B cols 0-127 @16K, 3=B 128-255 @48K), 8-row block blk.
    auto stage_op = [&](int ktn, int h, int blk) {
        const int dest = (ktn & 1) * 65536 + (h & 1) * 32768
                       + (h >> 1) * 16384 + blk * 1024;
        const char* sb = (h < 2) ? XbB : TbB;
        const int rc = ((h < 2) ? bm : bn) * 256 + (h & 1) * 128 + blk * 8 + rsub;
        const size_t src = (size_t)rc * 512 + (size_t)(ktn * 128 + sg16);
        __builtin_amdgcn_global_load_lds(
            (const AS1 void*)(sb + src), (AS3 void*)(smem + dest), 16, 0, 0);
    };
    // P0-unit (4 ops/wave, 32 KB): af0 rows (h0/h1 blks 0-7) + bf0 cols
    // (h2/h3 blks 0-3, 8-11).
    auto stageP0 = [&](int ktn) {
        #pragma unroll
        for (int c = 0; c < 4; ++c) {
            const int o = wid * 4 + c;        // 0..31
            int h, blk;
            if (o < 16) { h = o >> 3; blk = o & 7; }
            else { const int s = o & 15; h = 2 + (s >> 3);
                   const int bb = s & 7; blk = (bb & 3) + ((bb >> 2) << 3); }
            stage_op(ktn, h, blk);
        }
    };
    // P1-unit (2 ops/wave, 16 KB): bf1 cols (h2/h3 blks 4-7, 12-15).
    auto stageP1 = [&](int ktn) {
        #pragma unroll
        for (int c = 0; c < 2; ++c) {
            const int o = wid * 2 + c;        // 0..15
            const int bb = o & 7;
            stage_op(ktn, 2 + (o >> 3), 4 + (bb & 3) + ((bb >> 2) << 3));
        }
    };
    // P2-unit (2 ops/wave, 16 KB): af1 rows (h0/h1 blks 8-15).
    auto stageP2 = [&](int ktn) {
        #pragma unroll
        for (int c = 0; c < 2; ++c) {
            const int o = wid * 2 + c;        // 0..15
            stage_op(ktn, o >> 3, 8 + (o & 7));
        }
    };

    f32x4 acc[8][4];
    #pragma unroll
    for (int m = 0; m < 8; ++m)
        #pragma unroll
        for (int n = 0; n < 4; ++n) acc[m][n] = (f32x4)0.0f;

    // prologue: stage all three units of kt0 (8 ops/wave outstanding)
    stageP0(0); stageP1(0); stageP2(0);

    short8 af0[4][2], af1[4][2], bf0[2][2], bf1[2][2];

    #pragma unroll
    for (int kt = 0; kt < 4; ++kt) {
        const char* Abase = smem + (kt & 1) * 65536 + wr * 32768;
        const char* Bbase = smem + (kt & 1) * 65536 + 16384 + (wc >> 1) * 32768
                          + (wc & 1) * 8192;

        // ---- P0: issue P0u(kt+1); wait P0u(kt) [issued 4 phases ago] ----
        if (kt < 3) { stageP0(kt + 1);
                      asm volatile("s_waitcnt vmcnt(8)" ::: "memory"); }
        else          asm volatile("s_waitcnt vmcnt(4)" ::: "memory");
        asm volatile("s_barrier" ::: "memory");  // all waves' P0u(kt) landed
        #pragma unroll
        for (int m = 0; m < 4; ++m)
            #pragma unroll
            for (int ks = 0; ks < 2; ++ks)
                af0[m][ks] = *(const short8*)(Abase + (m * 16 + l15) * 128
                                              + (((ks * 4 + lg) ^ xr)) * 16);
        #pragma unroll
        for (int n = 0; n < 2; ++n)
            #pragma unroll
            for (int ks = 0; ks < 2; ++ks)
                bf0[n][ks] = *(const short8*)(Bbase + (n * 16 + l15) * 128
                                              + (((ks * 4 + lg) ^ xr)) * 16);
        __builtin_amdgcn_s_setprio(1);
        #pragma unroll
        for (int ks = 0; ks < 2; ++ks)
            #pragma unroll
            for (int m = 0; m < 4; ++m)
                #pragma unroll
                for (int n = 0; n < 2; ++n)
                    acc[m][n] = __builtin_amdgcn_mfma_f32_16x16x32_bf16(
                        af0[m][ks], bf0[n][ks], acc[m][n], 0, 0, 0);
        __builtin_amdgcn_s_setprio(0);

        // ---- P1: issue P1u(kt+1); wait P1u(kt); read bf1 ----
        if (kt < 3) { stageP1(kt + 1);
                      asm volatile("s_waitcnt vmcnt(8)" ::: "memory"); }
        else          asm volatile("s_waitcnt vmcnt(2)" ::: "memory");
        asm volatile("s_barrier" ::: "memory");
        #pragma unroll
        for (int n = 0; n < 2; ++n)
            #pragma unroll
            for (int ks = 0; ks < 2; ++ks)
                bf1[n][ks] = *(const short8*)(Bbase + (32 + n * 16 + l15) * 128
                                              + (((ks * 4 + lg) ^ xr)) * 16);
        __builtin_amdgcn_s_setprio(1);
        #pragma unroll
        for (int ks = 0; ks < 2; ++ks)
            #pragma unroll
            for (int m = 0; m < 4; ++m)
                #pragma unroll
                for (int n = 0; n < 2; ++n)
                    acc[m][2 + n] = __builtin_amdgcn_mfma_f32_16x16x32_bf16(
                        af0[m][ks], bf1[n][ks], acc[m][2 + n], 0, 0, 0);
        __builtin_amdgcn_s_setprio(0);

        // ---- P2: issue P2u(kt+1); wait P2u(kt); read af1 ----
        if (kt < 3) { stageP2(kt + 1);
                      asm volatile("s_waitcnt vmcnt(8)" ::: "memory"); }
        else          asm volatile("s_waitcnt vmcnt(0)" ::: "memory");
        asm volatile("s_barrier" ::: "memory");
        #pragma unroll
        for (int m = 0; m < 4; ++m)
            #pragma unroll
            for (int ks = 0; ks < 2; ++ks)
                af1[m][ks] = *(const short8*)(Abase + (64 + m * 16 + l15) * 128
                                              + (((ks * 4 + lg) ^ xr)) * 16);
        __builtin_amdgcn_s_setprio(1);
        #pragma unroll
        for (int ks = 0; ks < 2; ++ks)
            #pragma unroll
            for (int m = 0; m < 4; ++m)
                #pragma unroll
                for (int n = 0; n < 2; ++n)
                    acc[4 + m][2 + n] = __builtin_amdgcn_mfma_f32_16x16x32_bf16(
                        af1[m][ks], bf1[n][ks], acc[4 + m][2 + n], 0, 0, 0);
        __builtin_amdgcn_s_setprio(0);

        // ---- P3: register-only quadrant (af1 x bf0) — no barrier ----
        __builtin_amdgcn_s_setprio(1);
        #pragma unroll
        for (int ks = 0; ks < 2; ++ks)
            #pragma unroll
            for (int m = 0; m < 4; ++m)
                #pragma unroll
                for (int n = 0; n < 2; ++n)
                    acc[4 + m][n] = __builtin_amdgcn_mfma_f32_16x16x32_bf16(
                        af1[m][ks], bf0[n][ks], acc[4 + m][n], 0, 0, 0);
        __builtin_amdgcn_s_setprio(0);
    }

    // ---- Epilogue: exp2 + alpha-weighted row reduce ----
    const int rowbase = bm * 256 + wr * 128;
    float4 s1v[8];
    #pragma unroll
    for (int m = 0; m < 8; ++m)
        s1v[m] = *reinterpret_cast<const float4*>(sq1 + rowbase + m * 16 + lg * 4);
    float2 sa[4];
    #pragma unroll
    for (int n = 0; n < 4; ++n)
        sa[n] = sqal[bn * 256 + wc * 64 + n * 16 + l15];

    float amax = acc[0][0][0], s1m = s1v[0][0], s2m = sa[0].x;
    #pragma unroll
    for (int m = 0; m < 8; ++m)
        #pragma unroll
        for (int n = 0; n < 4; ++n)
            #pragma unroll
            for (int rr = 0; rr < 4; ++rr) amax = fmaxf(amax, acc[m][n][rr]);
    #pragma unroll
    for (int m = 0; m < 8; ++m)
        #pragma unroll
        for (int rr = 0; rr < 4; ++rr) s1m = fmaxf(s1m, s1v[m][rr]);
    #pragma unroll
    for (int n = 0; n < 4; ++n) s2m = fmaxf(s2m, sa[n].x);

    float psum[8][4];
    #pragma unroll
    for (int m = 0; m < 8; ++m)
        #pragma unroll
        for (int rr = 0; rr < 4; ++rr) psum[m][rr] = 0.0f;

    const float bound = fmaf(amax, K_ACC, s1m + s2m); // >= every arg (K_ACC>0)
    if (!__all(bound < SKIP_THR)) {
        #pragma unroll
        for (int m = 0; m < 8; ++m)
            #pragma unroll
            for (int n = 0; n < 4; ++n)
                #pragma unroll
                for (int rr = 0; rr < 4; ++rr) {
                    const float arg = fmaf(acc[m][n][rr], K_ACC, s1v[m][rr] + sa[n].x);
                    psum[m][rr] = fmaf(__builtin_amdgcn_exp2f(arg), sa[n].y, psum[m][rr]);
                }
    }

    // 16-lane (l15) shuffle reduce -> cross-wave (wc) via LDS.
    // red[] overlays buf0's A-region; its last LDS readers (kt=2) are
    // barrier-ordered before kt=3 P2, which precedes any epilogue write.
    float* red = (float*)smem;
    #pragma unroll
    for (int m = 0; m < 8; ++m) {
        float4 pv;
        #pragma unroll
        for (int rr = 0; rr < 4; ++rr) {
            float p = psum[m][rr];
            p += __shfl_xor(p, 1);
            p += __shfl_xor(p, 2);
            p += __shfl_xor(p, 4);
            p += __shfl_xor(p, 8);
            ((float*)&pv)[rr] = p;
        }
        if (l15 == 0)
            *reinterpret_cast<float4*>(&red[wc * 256 + wr * 128 + m * 16 + lg * 4]) = pv;
    }
    __syncthreads();
    if (tid < 256) {
        const float s = red[tid] + red[256 + tid] + red[512 + tid] + red[768 + tid];
        part[(size_t)bn * M_DIM + bm * 256 + tid] = s;
    }
}

// ---------------------------------------------------------------------------
// reduce: out[i] = sum over 32 col-slices of part[cs][i]. 16 blocks x 256.
// ---------------------------------------------------------------------------
__global__ __launch_bounds__(256) void reduce_kernel(
    const float* __restrict__ part, float* __restrict__ out)
{
    const int gi = blockIdx.x * 256 + threadIdx.x;
    float s = 0.0f;
    #pragma unroll
    for (int b = 0; b < NSLICE; ++b) s += part[(size_t)b * M_DIM + gi];
    out[gi] = s;
}

extern "C" void kernel_launch(void* const* d_in, const int* in_sizes, int n_in,
                              void* d_out, int out_size, void* d_ws, size_t ws_size,
                              hipStream_t stream)
{
    const float* X  = (const float*)d_in[0];
    const float* T  = (const float*)d_in[1];
    const float* al = (const float*)d_in[2];
    float* out = (float*)d_out;

    char* ws = (char*)d_ws;
    unsigned short* Xb = (unsigned short*)ws;                               // 2 MiB
    unsigned short* Tb = (unsigned short*)(ws + (size_t)M_DIM * D_DIM * 2); // 4 MiB
    float* sq1  = (float*)(ws + (size_t)(M_DIM + N_DIM) * D_DIM * 2);       // 16 KiB
    float2* sqal = (float2*)(sq1 + M_DIM);                                  // 64 KiB
    float* part = (float*)(sqal + N_DIM);                                   // 512 KiB

    prep_kernel<<<(M_DIM + N_DIM) / 4, 256, 0, stream>>>(X, T, al, Xb, Tb, sq1, sqal);
    gemm_kernel<<<(M_DIM / 256) * NSLICE, 512, 0, stream>>>(Xb, Tb, sq1, sqal, part);
    reduce_kernel<<<M_DIM / 256, 256, 0, stream>>>(part, out);
}